// Round 6
// baseline (678.228 us; speedup 1.0000x reference)
//
#include <hip/hip_runtime.h>
#include <hip/hip_cooperative_groups.h>
#include <hip/hip_fp16.h>
#include <math.h>

namespace cg = cooperative_groups;

#define N_NODES 100000
#define N_EDGES 3200000
#define IN_DIM 11
#define HID 32
#define HID2 16
#define SCHUNK 100352   // per-array stride in ws (multiple of 128, >= N_NODES+1)
#define BINSHIFT 8
#define BINSZ 256
#define NB 391          // ceil(100000/256) bins (256 nodes each)
#define CHUNK 4224      // edges per chunk (one chunk per block)
#define NCH 758         // ceil(3200000/4224); 758*4224 = 3201792 >= 3.2M

// LDS pool layout (bytes); peak 44160 -> 3 blocks/CU (132.5KB of 160KB)
#define OFF_SREC  0       // u32[CHUNK] sorted records   (16896)
#define OFF_SBINS 16896   // u16[CHUNK] sorted bins      (8448)
#define OFF_SBIN  25344   // u16[CHUNK] bin per edge     (8448)  [P1 only; reused P5]
#define OFF_SDL   33792   // u8 [CHUNK] dst-local        (4224)  [P1 only]
#define OFF_H     38016   // i32[512] hist/cursor
#define OFF_RL    40064   // i32[512] local sorted base  (persists P1->P4)
#define OFF_TMP   42112   // i32[512] scan scratch / gb
#define POOLSZ    44160

// ---------------- fused CSR build + xw1 (cooperative; one chunk per block) --------------
__global__ __launch_bounds__(512, 6) void k_build(
    const int* __restrict__ ei, int* __restrict__ cnthist,
    int* __restrict__ colsum, int* __restrict__ binbase,
    unsigned* __restrict__ binbuf, int* __restrict__ rowstart,
    float* __restrict__ dinv, int* __restrict__ csr_src,
    const float* __restrict__ x, const float* __restrict__ W1,
    __half* __restrict__ xwh1)
{
    cg::grid_group grid = cg::this_grid();
    __shared__ __align__(16) unsigned char pool[POOLSZ];
    unsigned*       srecS = (unsigned*)(pool + OFF_SREC);
    unsigned short* sbinS = (unsigned short*)(pool + OFF_SBINS);
    unsigned short* sbin  = (unsigned short*)(pool + OFF_SBIN);
    unsigned char*  sdl   = (unsigned char*)(pool + OFF_SDL);
    int* h   = (int*)(pool + OFF_H);
    int* rl  = (int*)(pool + OFF_RL);
    int* tmp = (int*)(pool + OFF_TMP);

    const int blk = blockIdx.x;
    const int t = threadIdx.x;
    const int b0 = blk * CHUNK;
    int n = N_EDGES - b0; if (n > CHUNK) n = CHUNK;

    // ---- P1: decode dst, hist, local sort into LDS; write per-(bin,chunk) counts ----
    h[t] = 0;
    __syncthreads();
    for (int e = t; e < n; e += 512) {
        int d = ei[N_EDGES + b0 + e];
        int b = d >> BINSHIFT;
        sbin[e] = (unsigned short)b;
        sdl[e]  = (unsigned char)(d & (BINSZ - 1));
        atomicAdd(&h[b], 1);
    }
    __syncthreads();
    int c = h[t];
    tmp[t] = c;
    __syncthreads();
    for (int off = 1; off < 512; off <<= 1) {
        int u = (t >= off) ? tmp[t - off] : 0;
        __syncthreads();
        tmp[t] += u;
        __syncthreads();
    }
    rl[t] = tmp[t] - c;   // chunk-local sorted base per bin (persists to P4)
    h[t] = 0;             // cursor
    if (t < NB) cnthist[t * NCH + blk] = c;
    __syncthreads();
    for (int e = t; e < n; e += 512) {
        int s = ei[b0 + e];                    // coalesced src read
        int b = sbin[e];
        int p = rl[b] + atomicAdd(&h[b], 1);
        srecS[p] = (unsigned)s | ((unsigned)sdl[e] << 17);  // s < 2^17
        sbinS[p] = (unsigned short)b;
    }
    grid.sync();

    // ---- P2: per-bin exclusive scan over chunks, in place (blocks 0..NB-1) ----
    if (blk < NB) {
        int i0 = t * 2, i1 = t * 2 + 1;
        int v0 = (i0 < NCH) ? cnthist[blk * NCH + i0] : 0;
        int v1 = (i1 < NCH) ? cnthist[blk * NCH + i1] : 0;
        int s2 = v0 + v1;
        tmp[t] = s2;
        __syncthreads();
        for (int off = 1; off < 512; off <<= 1) {
            int u = (t >= off) ? tmp[t - off] : 0;
            __syncthreads();
            tmp[t] += u;
            __syncthreads();
        }
        int base = tmp[t] - s2;
        if (i0 < NCH) cnthist[blk * NCH + i0] = base;
        if (i1 < NCH) cnthist[blk * NCH + i1] = base + v0;
        if (t == 511) colsum[blk] = tmp[511];
    }
    grid.sync();

    // ---- P3: scan of bin totals -> binbase (block 0) ----
    if (blk == 0) {
        int v = (t < NB) ? colsum[t] : 0;
        tmp[t] = v;
        __syncthreads();
        for (int off = 1; off < 512; off <<= 1) {
            int u = (t >= off) ? tmp[t - off] : 0;
            __syncthreads();
            tmp[t] += u;
            __syncthreads();
        }
        if (t < NB) binbase[t] = tmp[t] - v;
        if (t == 0) binbase[NB] = N_EDGES;
    }
    grid.sync();

    // ---- P4: dump LDS-sorted records to binbuf runs (clustered writes) ----
    if (t < NB) tmp[t] = binbase[t] + cnthist[t * NCH + blk];  // global run base
    __syncthreads();
    for (int p = t; p < n; p += 512) {
        int b = sbinS[p];
        binbuf[tmp[b] + (p - rl[b])] = srecS[p];
    }
    grid.sync();

    // ---- P5: per-bin node counting sort -> csr_src/rowstart/dinv (half-bin tasks) ----
    int* cnt  = (int*)(pool + OFF_SBIN);
    int* rloc = (int*)(pool + OFF_SBIN + 1024);
    int* cur  = (int*)(pool + OFF_SBIN + 2048);
    int* tm2  = (int*)(pool + OFF_SBIN + 3072);
    for (int task = blk; task < 2 * NB; task += NCH) {
        int b = task >> 1, half = task & 1;
        int ebeg = binbase[b], eend = binbase[b + 1];
        if (t < BINSZ) cnt[t] = 0;
        __syncthreads();
        for (int e = ebeg + t; e < eend; e += 512)
            atomicAdd(&cnt[binbuf[e] >> 17], 1);
        __syncthreads();
        int cc = (t < BINSZ) ? cnt[t] : 0;
        if (t < BINSZ) tm2[t] = cc;
        __syncthreads();
        for (int off = 1; off < BINSZ; off <<= 1) {
            int u = (t < BINSZ && t >= off) ? tm2[t - off] : 0;
            __syncthreads();
            if (t < BINSZ) tm2[t] += u;
            __syncthreads();
        }
        if (t < BINSZ) {
            rloc[t] = tm2[t] - cc;
            cur[t] = 0;
            int node = b * BINSZ + t;
            if ((t >> 7) == half && node < N_NODES) {
                rowstart[node] = ebeg + rloc[t];
                dinv[node] = rsqrtf((float)cc + 1.0f);  // +1 self-loop
            }
        }
        __syncthreads();
        for (int e = ebeg + t; e < eend; e += 512) {
            unsigned vv = binbuf[e];
            int dl = vv >> 17;
            if ((dl >> 7) == half) {
                int p = ebeg + rloc[dl] + atomicAdd(&cur[dl], 1);
                csr_src[p] = (int)(vv & 0x1FFFFu);
            }
        }
        __syncthreads();
    }
    if (blk == 0 && t == 0) rowstart[N_NODES] = N_EDGES;  // sentinel
    grid.sync();

    // ---- P6: xw1 -- XWH1 = fp16(dinv .* (x @ W1)) ----
    float* sW = (float*)(pool + OFF_SREC);           // 352 floats
    float* sx = (float*)(pool + OFF_SREC + 2048);    // 176 floats
    for (int i = t; i < IN_DIM * HID; i += 512) sW[i] = W1[i];
    __syncthreads();
    for (int task = blk; task < N_NODES / 16; task += NCH) {  // 6250 tasks of 16 nodes
        if (t < 16 * IN_DIM) sx[t] = x[task * 16 * IN_DIM + t];
        __syncthreads();
        int ln = t >> 5, j = t & 31;
        int node = task * 16 + ln;
        float acc = 0.0f;
#pragma unroll
        for (int k = 0; k < IN_DIM; ++k)
            acc += sx[ln * IN_DIM + k] * sW[k * HID + j];
        xwh1[node * HID + j] = __float2half(dinv[node] * acc);
        __syncthreads();
    }
}

// ---------------- wide edge gather (octet decomposition, unchanged from r5) ----------------
__device__ __forceinline__ void accum8(float* __restrict__ acc, const uint4 v) {
    float2 f0 = __half22float2(*(const __half2*)&v.x);
    float2 f1 = __half22float2(*(const __half2*)&v.y);
    float2 f2 = __half22float2(*(const __half2*)&v.z);
    float2 f3 = __half22float2(*(const __half2*)&v.w);
    acc[0] += f0.x; acc[1] += f0.y;
    acc[2] += f1.x; acc[3] += f1.y;
    acc[4] += f2.x; acc[5] += f2.y;
    acc[6] += f3.x; acc[7] += f3.y;
}

__device__ __forceinline__ void edge_accum8(int beg, int end, int q, int oj,
                                            const int* __restrict__ csr_src,
                                            const __half* __restrict__ xwh,
                                            float* __restrict__ acc) {
#pragma unroll
    for (int k = 0; k < 8; ++k) acc[k] = 0.0f;
    int e = beg;
    for (; e + 32 <= end; e += 32) {
        int s0 = csr_src[e + q];
        int s1 = csr_src[e + 8 + q];
        int s2 = csr_src[e + 16 + q];
        int s3 = csr_src[e + 24 + q];
        uint4 v0 = *(const uint4*)(xwh + ((s0 << 5) | oj));
        uint4 v1 = *(const uint4*)(xwh + ((s1 << 5) | oj));
        uint4 v2 = *(const uint4*)(xwh + ((s2 << 5) | oj));
        uint4 v3 = *(const uint4*)(xwh + ((s3 << 5) | oj));
        accum8(acc, v0); accum8(acc, v1); accum8(acc, v2); accum8(acc, v3);
    }
    if (e + 16 <= end) {
        int s0 = csr_src[e + q];
        int s1 = csr_src[e + 8 + q];
        uint4 v0 = *(const uint4*)(xwh + ((s0 << 5) | oj));
        uint4 v1 = *(const uint4*)(xwh + ((s1 << 5) | oj));
        accum8(acc, v0); accum8(acc, v1);
        e += 16;
    }
    if (e + 8 <= end) {
        int s0 = csr_src[e + q];
        uint4 v0 = *(const uint4*)(xwh + ((s0 << 5) | oj));
        accum8(acc, v0);
        e += 8;
    }
    if (e + q < end) {  // masked tail
        int s0 = csr_src[e + q];
        uint4 v0 = *(const uint4*)(xwh + ((s0 << 5) | oj));
        accum8(acc, v0);
    }
#pragma unroll
    for (int m = 4; m <= 16; m <<= 1) {
#pragma unroll
        for (int k = 0; k < 8; ++k) acc[k] += __shfl_xor(acc[k], m);
    }
}

// ---------------- layer-1 gather fused with bias1+relu and the W2 transform ---------------
__global__ __launch_bounds__(256) void k_gather_xw2(const int* __restrict__ rowstart,
                                                    const float* __restrict__ dinv,
                                                    const int* __restrict__ csr_src,
                                                    const __half* __restrict__ xwh1,
                                                    const float* __restrict__ b1,
                                                    const float* __restrict__ W2,
                                                    __half* __restrict__ xwh2) {
    __shared__ float sW2[HID * HID];
    __shared__ float sA[8][33];
    __shared__ float sH[8][33];
    for (int i = threadIdx.x; i < HID * HID; i += 256) sW2[i] = W2[i];

    int ln = threadIdx.x >> 5;
    int node = blockIdx.x * 8 + ln;
    int l = threadIdx.x & 31;
    int q = l >> 2;
    int oj = (l & 3) << 3;

    float acc[8];
    edge_accum8(rowstart[node], rowstart[node + 1], q, oj, csr_src, xwh1, acc);
    if (q == 0) {
#pragma unroll
        for (int k = 0; k < 8; ++k) sA[ln][oj + k] = acc[k];
    }
    __syncthreads();

    int j = l;
    float dd = dinv[node];
    float hv = dd * (sA[ln][j] + __half2float(xwh1[node * HID + j])) + b1[j];
    sH[ln][j] = hv > 0.0f ? hv : 0.0f;
    __syncthreads();

    float a2 = 0.0f;
#pragma unroll
    for (int k = 0; k < HID; ++k) a2 += sH[ln][k] * sW2[k * HID + j];
    xwh2[node * HID + j] = __float2half(dd * a2);
}

// ---------------- layer-2 gather fused with bias2+relu and the output MLP ----------------
__global__ __launch_bounds__(256) void k_gather_mlp(const int* __restrict__ rowstart,
                                                    const float* __restrict__ dinv,
                                                    const int* __restrict__ csr_src,
                                                    const __half* __restrict__ xwh,
                                                    const float* __restrict__ b2,
                                                    const float* __restrict__ Wo1,
                                                    const float* __restrict__ bo1,
                                                    const float* __restrict__ Wo2,
                                                    const float* __restrict__ bo2,
                                                    float* __restrict__ out) {
    __shared__ float sW1[HID * HID2];
    __shared__ float sb1[HID2];
    __shared__ float sW2v[HID2];
    __shared__ float sb2[HID];
    __shared__ float sA[8][33];
    __shared__ float sH[8][33];
    for (int i = threadIdx.x; i < HID * HID2; i += 256) sW1[i] = Wo1[i];
    if (threadIdx.x < HID2) {
        sb1[threadIdx.x] = bo1[threadIdx.x];
        sW2v[threadIdx.x] = Wo2[threadIdx.x];
    }
    if (threadIdx.x < HID) sb2[threadIdx.x] = b2[threadIdx.x];

    int ln = threadIdx.x >> 5;
    int node = blockIdx.x * 8 + ln;
    int l = threadIdx.x & 31;
    int q = l >> 2;
    int oj = (l & 3) << 3;

    float acc[8];
    edge_accum8(rowstart[node], rowstart[node + 1], q, oj, csr_src, xwh, acc);
    if (q == 0) {
#pragma unroll
        for (int k = 0; k < 8; ++k) sA[ln][oj + k] = acc[k];
    }
    __syncthreads();

    int j = l;
    float dd = dinv[node];
    float hv = dd * (sA[ln][j] + __half2float(xwh[node * HID + j])) + sb2[j];
    sH[ln][j] = hv > 0.0f ? hv : 0.0f;
    __syncthreads();

    float val = 0.0f;
    if (j < HID2) {
        float a = sb1[j];
#pragma unroll
        for (int k = 0; k < HID; ++k) a += sH[ln][k] * sW1[k * HID2 + j];
        a = a > 0.0f ? a : (expf(a) - 1.0f);  // elu alpha=1
        val = a * sW2v[j];
    }
#pragma unroll
    for (int d = 16; d >= 1; d >>= 1) val += __shfl_down(val, d, 32);
    if (j == 0) out[node] = val + bo2[0];
}

extern "C" void kernel_launch(void* const* d_in, const int* in_sizes, int n_in,
                              void* d_out, int out_size, void* d_ws, size_t ws_size,
                              hipStream_t stream) {
    const float* x   = (const float*)d_in[0];
    const int*   ei  = (const int*)d_in[1];
    const float* W1  = (const float*)d_in[3];
    const float* b1  = (const float*)d_in[4];
    const float* W2  = (const float*)d_in[5];
    const float* b2  = (const float*)d_in[6];
    const float* Wo1 = (const float*)d_in[7];
    const float* bo1 = (const float*)d_in[8];
    const float* Wo2 = (const float*)d_in[9];
    const float* bo2 = (const float*)d_in[10];
    float* out = (float*)d_out;

    // ws layout (4B units):
    // colsum[512] | binbase[512] | rowstart[SCHUNK] | dinv[SCHUNK]
    // | csr_src[E] (cnthist[NB*NCH]=1.2MB aliases here; dead before P5 writes)
    // | binbuf[E] | XWH1[N*HID fp16] | XWH2[N*HID fp16]
    int*      colsum   = (int*)d_ws;
    int*      binbase  = colsum + 512;
    int*      rowstart = binbase + 512;
    float*    dinv     = (float*)(rowstart + SCHUNK);
    int*      csr_src  = (int*)(dinv + SCHUNK);
    unsigned* binbuf   = (unsigned*)(csr_src + N_EDGES);
    __half*   XWH1     = (__half*)(binbuf + N_EDGES);
    __half*   XWH2     = XWH1 + (size_t)N_NODES * HID;
    int*      cnthist  = csr_src;   // alias: NB*NCH = 296378 ints << N_EDGES

    const int BT = 256;
    int gG = N_NODES / 8;   // 12500 (exact)

    // fused build+xw1: one cooperative launch (758 blocks x 512 thr, 3 blocks/CU)
    void* kargs[] = { (void*)&ei, (void*)&cnthist, (void*)&colsum, (void*)&binbase,
                      (void*)&binbuf, (void*)&rowstart, (void*)&dinv, (void*)&csr_src,
                      (void*)&x, (void*)&W1, (void*)&XWH1 };
    hipLaunchCooperativeKernel((const void*)k_build, dim3(NCH), dim3(512),
                               kargs, 0, stream);

    // layer 1 (+ fused W2): XWH2 = fp16(dinv.*(relu(gather+b1)@W2))
    k_gather_xw2<<<gG, BT, 0, stream>>>(rowstart, dinv, csr_src, XWH1, b1, W2, XWH2);

    // layer 2 + head: out = MLP(relu(dinv.*gather(XWH2) + b2))
    k_gather_mlp<<<gG, BT, 0, stream>>>(rowstart, dinv, csr_src, XWH2,
                                        b2, Wo1, bo1, Wo2, bo2, out);
}

// Round 7
// 250.554 us; speedup vs baseline: 2.7069x; 2.7069x over previous
//
#include <hip/hip_runtime.h>
#include <hip/hip_fp16.h>
#include <math.h>

#define N_NODES 100000
#define N_EDGES 3200000
#define IN_DIM 11
#define HID 32
#define HID2 16
#define SCHUNK 100352   // per-array stride in ws (multiple of 128, >= N_NODES+1)
#define BINSHIFT 8
#define BINSZ 256
#define NB 391          // ceil(100000/256) bins (256 nodes each)
#define CHUNK 4096      // edges per chunk
#define NCH 782         // ceil(3200000/4096) chunks

// ---------------- wave-shuffle scan utilities (wave = 64) ----------------
__device__ __forceinline__ int wincl(int v) {
    int lane = threadIdx.x & 63;
#pragma unroll
    for (int d = 1; d < 64; d <<= 1) {
        int u = __shfl_up(v, d, 64);
        v += (lane >= d) ? u : 0;
    }
    return v;
}

// exclusive prefix of v across 512 threads; wtot = LDS int[8]; 2 barriers
__device__ __forceinline__ int blkexcl512(int v, int* wtot) {
    int t = threadIdx.x, lane = t & 63, w = t >> 6;
    int inc = wincl(v);
    if (lane == 63) wtot[w] = inc;
    __syncthreads();
    if (t < 8) {
        int x = wtot[t], ix = x;
#pragma unroll
        for (int d = 1; d < 8; d <<= 1) {
            int u = __shfl_up(ix, d, 64);
            ix += (lane >= d) ? u : 0;
        }
        wtot[t] = ix - x;   // exclusive wave base
    }
    __syncthreads();
    return inc - v + wtot[w];
}

// ---------------- binned CSR build ----------------
// Pass 1: per-chunk per-bin counts -> cnthist[bin][chunk]  (no global atomics)
__global__ __launch_bounds__(256) void k_hist(const int* __restrict__ ei,
                                              int* __restrict__ cnthist) {
    __shared__ int h[NB];
    int t = threadIdx.x;
    for (int i = t; i < NB; i += 256) h[i] = 0;
    __syncthreads();
    int b0 = blockIdx.x * CHUNK;
    int n = N_EDGES - b0; if (n > CHUNK) n = CHUNK;   // always multiple of 4
    for (int e = t * 4; e < n; e += 1024) {
        int4 d4 = *(const int4*)(ei + N_EDGES + b0 + e);
        atomicAdd(&h[d4.x >> BINSHIFT], 1);
        atomicAdd(&h[d4.y >> BINSHIFT], 1);
        atomicAdd(&h[d4.z >> BINSHIFT], 1);
        atomicAdd(&h[d4.w >> BINSHIFT], 1);
    }
    __syncthreads();
    for (int i = t; i < NB; i += 256)
        cnthist[i * NCH + blockIdx.x] = h[i];
}

// Pass 2: per-bin exclusive scan over chunks (in-place), bin totals out.
__global__ __launch_bounds__(256) void k_colscan(int* __restrict__ cnthist,
                                                 int* __restrict__ colsum) {
    __shared__ int wtot[4];
    int i = blockIdx.x;   // bin
    int t = threadIdx.x;
    int lane = t & 63;
    int v[4];
    int s4 = 0;
#pragma unroll
    for (int u = 0; u < 4; ++u) {
        int idx = t * 4 + u;
        v[u] = (idx < NCH) ? cnthist[i * NCH + idx] : 0;
        s4 += v[u];
    }
    int inc = wincl(s4);
    if (lane == 63) wtot[t >> 6] = inc;
    __syncthreads();
    if (t < 4) {
        int x = wtot[t], ix = x;
#pragma unroll
        for (int d = 1; d < 4; d <<= 1) {
            int u2 = __shfl_up(ix, d, 64);
            ix += (lane >= d) ? u2 : 0;
        }
        wtot[t] = ix - x;
    }
    __syncthreads();
    int base = inc - s4 + wtot[t >> 6];   // exclusive across 4-groups
#pragma unroll
    for (int u = 0; u < 4; ++u) {
        int idx = t * 4 + u;
        if (idx < NCH) cnthist[i * NCH + idx] = base;
        base += v[u];
    }
    if (t == 255) colsum[i] = base;       // inclusive total
}

// Pass 3: scan of 391 bin totals -> binbase (single block)
__global__ __launch_bounds__(512) void k_scanbins(const int* __restrict__ colsum,
                                                  int* __restrict__ binbase) {
    __shared__ int wtot[8];
    int t = threadIdx.x;
    int v = (t < NB) ? colsum[t] : 0;
    int pre = blkexcl512(v, wtot);
    if (t < NB) binbase[t] = pre;
    if (t == 0) binbase[NB] = N_EDGES;   // sentinel
}

// Pass 4: scatter edges into bin buckets.  Chunk is bin-sorted in LDS first,
// then dumped linearly (clustered writes; kills partial-line eviction RMW).
__global__ __launch_bounds__(512) void k_binscatter(const int* __restrict__ ei,
                                                    const int* __restrict__ binbase,
                                                    const int* __restrict__ cnthist,
                                                    unsigned* __restrict__ binbuf) {
    __shared__ unsigned short sbin[CHUNK];   // bin per edge (load order)
    __shared__ unsigned char  sdl[CHUNK];    // dst-local per edge
    __shared__ unsigned       srecS[CHUNK];  // records at sorted position
    __shared__ unsigned short sbinS[CHUNK];  // bin at sorted position
    __shared__ int h[NB], rl[NB], gb[NB];
    __shared__ int wtot[8];
    int t = threadIdx.x;
    int b0 = blockIdx.x * CHUNK;
    int n = N_EDGES - b0; if (n > CHUNK) n = CHUNK;
    for (int i = t; i < NB; i += 512) h[i] = 0;
    __syncthreads();
    for (int e = t; e < n; e += 512) {
        int d = ei[N_EDGES + b0 + e];
        int b = d >> BINSHIFT;
        sbin[e] = (unsigned short)b;
        sdl[e]  = (unsigned char)(d & (BINSZ - 1));
        atomicAdd(&h[b], 1);
    }
    __syncthreads();
    int c = (t < NB) ? h[t] : 0;
    int pre = blkexcl512(c, wtot);   // 2 barriers (was 18)
    if (t < NB) {
        rl[t] = pre;                                        // local sorted base
        gb[t] = binbase[t] + cnthist[t * NCH + blockIdx.x]; // global dump base
        h[t] = 0;                                           // reuse as cursor
    }
    __syncthreads();
    for (int e = t; e < n; e += 512) {
        int s = ei[b0 + e];            // coalesced re-read of src row
        int b = sbin[e];
        int p = rl[b] + atomicAdd(&h[b], 1);
        srecS[p] = (unsigned)s | ((unsigned)sdl[e] << 17);  // s < 2^17
        sbinS[p] = (unsigned short)b;
    }
    __syncthreads();
    for (int p = t; p < n; p += 512) {
        int b = sbinS[p];
        binbuf[gb[b] + (p - rl[b])] = srecS[p];
    }
}

// Pass 5: within each bin, per-node counting sort -> csr_src, rowstart, dinv.
// Half-bin split (782 blocks, no tail); 512 threads halve the latency chain.
__global__ __launch_bounds__(512) void k_binfill(const unsigned* __restrict__ binbuf,
                                                 const int* __restrict__ binbase,
                                                 int* __restrict__ rowstart,
                                                 float* __restrict__ dinv,
                                                 int* __restrict__ csr_src) {
    int bb = blockIdx.x;
    int b = bb >> 1;        // bin
    int half = bb & 1;      // node range [half*128, half*128+128)
    int t = threadIdx.x;
    __shared__ int cnt[BINSZ], rloc[BINSZ], cur[BINSZ], wtot[8];
    int ebeg = binbase[b], eend = binbase[b + 1];
    if (t < BINSZ) cnt[t] = 0;
    __syncthreads();
    for (int e = ebeg + t; e < eend; e += 512)
        atomicAdd(&cnt[binbuf[e] >> 17], 1);
    __syncthreads();
    int c = (t < BINSZ) ? cnt[t] : 0;
    int pre = blkexcl512(c, wtot);   // 2 barriers (was 16)
    if (t < BINSZ) {
        rloc[t] = pre;
        cur[t] = 0;
        int node = b * BINSZ + t;
        if ((t >> 7) == half && node < N_NODES) {
            rowstart[node] = ebeg + pre;
            dinv[node] = rsqrtf((float)c + 1.0f);  // +1 self-loop
        }
    }
    if (bb == 0 && t == 0) rowstart[N_NODES] = N_EDGES;  // sentinel
    __syncthreads();
    for (int e = ebeg + t; e < eend; e += 512) {
        unsigned vv = binbuf[e];
        int dl = vv >> 17;
        if ((dl >> 7) == half) {
            int p = ebeg + rloc[dl] + atomicAdd(&cur[dl], 1);
            csr_src[p] = (int)(vv & 0x1FFFFu);
        }
    }
}

// ---------------- dense transform 1 (write dinv-scaled fp16, interleaved [node*32+j]) -----
__global__ void k_xw1(const float* __restrict__ x, const float* __restrict__ W1,
                      const float* __restrict__ dinv, __half* __restrict__ xwh) {
    int t = blockIdx.x * blockDim.x + threadIdx.x;
    int node = t >> 5;
    int j = t & 31;
    __shared__ float sW[IN_DIM * HID];
    __shared__ float sx[8 * IN_DIM];
    for (int i = threadIdx.x; i < IN_DIM * HID; i += 256) sW[i] = W1[i];
    int base = blockIdx.x * 8;
    if (threadIdx.x < 8 * IN_DIM) sx[threadIdx.x] = x[base * IN_DIM + threadIdx.x];
    __syncthreads();
    int ln = node - base;
    float acc = 0.0f;
#pragma unroll
    for (int k = 0; k < IN_DIM; ++k)
        acc += sx[ln * IN_DIM + k] * sW[k * HID + j];
    xwh[t] = __float2half(dinv[node] * acc);
}

// ---------------- wide edge gather (octet decomposition, unchanged) ----------------
__device__ __forceinline__ void accum8(float* __restrict__ acc, const uint4 v) {
    float2 f0 = __half22float2(*(const __half2*)&v.x);
    float2 f1 = __half22float2(*(const __half2*)&v.y);
    float2 f2 = __half22float2(*(const __half2*)&v.z);
    float2 f3 = __half22float2(*(const __half2*)&v.w);
    acc[0] += f0.x; acc[1] += f0.y;
    acc[2] += f1.x; acc[3] += f1.y;
    acc[4] += f2.x; acc[5] += f2.y;
    acc[6] += f3.x; acc[7] += f3.y;
}

__device__ __forceinline__ void edge_accum8(int beg, int end, int q, int oj,
                                            const int* __restrict__ csr_src,
                                            const __half* __restrict__ xwh,
                                            float* __restrict__ acc) {
#pragma unroll
    for (int k = 0; k < 8; ++k) acc[k] = 0.0f;
    int e = beg;
    for (; e + 32 <= end; e += 32) {
        int s0 = csr_src[e + q];
        int s1 = csr_src[e + 8 + q];
        int s2 = csr_src[e + 16 + q];
        int s3 = csr_src[e + 24 + q];
        uint4 v0 = *(const uint4*)(xwh + ((s0 << 5) | oj));
        uint4 v1 = *(const uint4*)(xwh + ((s1 << 5) | oj));
        uint4 v2 = *(const uint4*)(xwh + ((s2 << 5) | oj));
        uint4 v3 = *(const uint4*)(xwh + ((s3 << 5) | oj));
        accum8(acc, v0); accum8(acc, v1); accum8(acc, v2); accum8(acc, v3);
    }
    if (e + 16 <= end) {
        int s0 = csr_src[e + q];
        int s1 = csr_src[e + 8 + q];
        uint4 v0 = *(const uint4*)(xwh + ((s0 << 5) | oj));
        uint4 v1 = *(const uint4*)(xwh + ((s1 << 5) | oj));
        accum8(acc, v0); accum8(acc, v1);
        e += 16;
    }
    if (e + 8 <= end) {
        int s0 = csr_src[e + q];
        uint4 v0 = *(const uint4*)(xwh + ((s0 << 5) | oj));
        accum8(acc, v0);
        e += 8;
    }
    if (e + q < end) {  // masked tail
        int s0 = csr_src[e + q];
        uint4 v0 = *(const uint4*)(xwh + ((s0 << 5) | oj));
        accum8(acc, v0);
    }
#pragma unroll
    for (int m = 4; m <= 16; m <<= 1) {
#pragma unroll
        for (int k = 0; k < 8; ++k) acc[k] += __shfl_xor(acc[k], m);
    }
}

// ---------------- layer-1 gather fused with bias1+relu and the W2 transform ---------------
__global__ __launch_bounds__(256) void k_gather_xw2(const int* __restrict__ rowstart,
                                                    const float* __restrict__ dinv,
                                                    const int* __restrict__ csr_src,
                                                    const __half* __restrict__ xwh1,
                                                    const float* __restrict__ b1,
                                                    const float* __restrict__ W2,
                                                    __half* __restrict__ xwh2) {
    __shared__ float sW2[HID * HID];
    __shared__ float sA[8][33];
    __shared__ float sH[8][33];
    for (int i = threadIdx.x; i < HID * HID; i += 256) sW2[i] = W2[i];

    int ln = threadIdx.x >> 5;
    int node = blockIdx.x * 8 + ln;
    int l = threadIdx.x & 31;
    int q = l >> 2;
    int oj = (l & 3) << 3;

    float acc[8];
    edge_accum8(rowstart[node], rowstart[node + 1], q, oj, csr_src, xwh1, acc);
    if (q == 0) {
#pragma unroll
        for (int k = 0; k < 8; ++k) sA[ln][oj + k] = acc[k];
    }
    __syncthreads();

    int j = l;
    float dd = dinv[node];
    float hv = dd * (sA[ln][j] + __half2float(xwh1[node * HID + j])) + b1[j];
    sH[ln][j] = hv > 0.0f ? hv : 0.0f;
    __syncthreads();

    float a2 = 0.0f;
#pragma unroll
    for (int k = 0; k < HID; ++k) a2 += sH[ln][k] * sW2[k * HID + j];
    xwh2[node * HID + j] = __float2half(dd * a2);
}

// ---------------- layer-2 gather fused with bias2+relu and the output MLP ----------------
__global__ __launch_bounds__(256) void k_gather_mlp(const int* __restrict__ rowstart,
                                                    const float* __restrict__ dinv,
                                                    const int* __restrict__ csr_src,
                                                    const __half* __restrict__ xwh,
                                                    const float* __restrict__ b2,
                                                    const float* __restrict__ Wo1,
                                                    const float* __restrict__ bo1,
                                                    const float* __restrict__ Wo2,
                                                    const float* __restrict__ bo2,
                                                    float* __restrict__ out) {
    __shared__ float sW1[HID * HID2];
    __shared__ float sb1[HID2];
    __shared__ float sW2v[HID2];
    __shared__ float sb2[HID];
    __shared__ float sA[8][33];
    __shared__ float sH[8][33];
    for (int i = threadIdx.x; i < HID * HID2; i += 256) sW1[i] = Wo1[i];
    if (threadIdx.x < HID2) {
        sb1[threadIdx.x] = bo1[threadIdx.x];
        sW2v[threadIdx.x] = Wo2[threadIdx.x];
    }
    if (threadIdx.x < HID) sb2[threadIdx.x] = b2[threadIdx.x];

    int ln = threadIdx.x >> 5;
    int node = blockIdx.x * 8 + ln;
    int l = threadIdx.x & 31;
    int q = l >> 2;
    int oj = (l & 3) << 3;

    float acc[8];
    edge_accum8(rowstart[node], rowstart[node + 1], q, oj, csr_src, xwh, acc);
    if (q == 0) {
#pragma unroll
        for (int k = 0; k < 8; ++k) sA[ln][oj + k] = acc[k];
    }
    __syncthreads();

    int j = l;
    float dd = dinv[node];
    float hv = dd * (sA[ln][j] + __half2float(xwh[node * HID + j])) + sb2[j];
    sH[ln][j] = hv > 0.0f ? hv : 0.0f;
    __syncthreads();

    float val = 0.0f;
    if (j < HID2) {
        float a = sb1[j];
#pragma unroll
        for (int k = 0; k < HID; ++k) a += sH[ln][k] * sW1[k * HID2 + j];
        a = a > 0.0f ? a : (expf(a) - 1.0f);  // elu alpha=1
        val = a * sW2v[j];
    }
#pragma unroll
    for (int d = 16; d >= 1; d >>= 1) val += __shfl_down(val, d, 32);
    if (j == 0) out[node] = val + bo2[0];
}

extern "C" void kernel_launch(void* const* d_in, const int* in_sizes, int n_in,
                              void* d_out, int out_size, void* d_ws, size_t ws_size,
                              hipStream_t stream) {
    const float* x   = (const float*)d_in[0];
    const int*   ei  = (const int*)d_in[1];
    const float* W1  = (const float*)d_in[3];
    const float* b1  = (const float*)d_in[4];
    const float* W2  = (const float*)d_in[5];
    const float* b2  = (const float*)d_in[6];
    const float* Wo1 = (const float*)d_in[7];
    const float* bo1 = (const float*)d_in[8];
    const float* Wo2 = (const float*)d_in[9];
    const float* bo2 = (const float*)d_in[10];
    float* out = (float*)d_out;

    // ws layout (4B units):
    // colsum[512] | binbase[512] | rowstart[SCHUNK] | dinv[SCHUNK]
    // | csr_src[E] (cnthist[NB*NCH]=1.2MB aliases here; dead before binfill writes)
    // | binbuf[E] | XWH1[N*HID fp16] | XWH2[N*HID fp16]
    int*      colsum   = (int*)d_ws;
    int*      binbase  = colsum + 512;
    int*      rowstart = binbase + 512;
    float*    dinv     = (float*)(rowstart + SCHUNK);
    int*      csr_src  = (int*)(dinv + SCHUNK);
    unsigned* binbuf   = (unsigned*)(csr_src + N_EDGES);
    __half*   XWH1     = (__half*)(binbuf + N_EDGES);
    __half*   XWH2     = XWH1 + (size_t)N_NODES * HID;
    int*      cnthist  = csr_src;   // alias: NB*NCH = 305762 ints << N_EDGES

    const int BT = 256;
    int gNH  = (N_NODES * HID + BT - 1) / BT;       // 12500
    int gG   = N_NODES / 8;                         // 12500 (exact)

    // binned CSR build: hist -> colscan -> binscan -> staged scatter -> fill
    k_hist      <<<NCH, BT, 0, stream>>>(ei, cnthist);
    k_colscan   <<<NB, BT, 0, stream>>>(cnthist, colsum);
    k_scanbins  <<<1, 512, 0, stream>>>(colsum, binbase);
    k_binscatter<<<NCH, 512, 0, stream>>>(ei, binbase, cnthist, binbuf);
    k_binfill   <<<2 * NB, 512, 0, stream>>>(binbuf, binbase, rowstart, dinv, csr_src);

    // layer 1 (+ fused W2): XWH1 = fp16(dinv.*(x@W1)); XWH2 = fp16(dinv.*(relu(gather+b1)@W2))
    k_xw1<<<gNH, BT, 0, stream>>>(x, W1, dinv, XWH1);
    k_gather_xw2<<<gG, BT, 0, stream>>>(rowstart, dinv, csr_src, XWH1, b1, W2, XWH2);

    // layer 2 + head: out = MLP(relu(dinv.*gather(XWH2) + b2))
    k_gather_mlp<<<gG, BT, 0, stream>>>(rowstart, dinv, csr_src, XWH2,
                                        b2, Wo1, bo1, Wo2, bo2, out);
}

// Round 8
// 239.421 us; speedup vs baseline: 2.8328x; 1.0465x over previous
//
#include <hip/hip_runtime.h>
#include <hip/hip_fp16.h>
#include <math.h>

#define N_NODES 100000
#define N_EDGES 3200000
#define IN_DIM 11
#define HID 32
#define HID2 16
#define SCHUNK 100352   // per-array stride in ws (multiple of 128, >= N_NODES+1)
#define BINSHIFT 8
#define BINSZ 256
#define NB 391          // ceil(100000/256) bins (256 nodes each)
#define CHUNK 6144      // edges per chunk
#define NCH 521         // ceil(3200000/6144); 521*6144 = 3201024
#define NCH1 522        // cnthist row stride (incl. sentinel column)
#define FCAP 9216       // binfill LDS staging capacity (avg bin = 8184)

// ---------------- wave-shuffle scan utilities (wave = 64) ----------------
__device__ __forceinline__ int wincl(int v) {
    int lane = threadIdx.x & 63;
#pragma unroll
    for (int d = 1; d < 64; d <<= 1) {
        int u = __shfl_up(v, d, 64);
        v += (lane >= d) ? u : 0;
    }
    return v;
}

// exclusive prefix of v across 512 threads; wtot = LDS int[8]; 2 barriers
__device__ __forceinline__ int blkexcl512(int v, int* wtot) {
    int t = threadIdx.x, lane = t & 63, w = t >> 6;
    int inc = wincl(v);
    if (lane == 63) wtot[w] = inc;
    __syncthreads();
    if (t < 8) {
        int x = wtot[t], ix = x;
#pragma unroll
        for (int d = 1; d < 8; d <<= 1) {
            int u = __shfl_up(ix, d, 64);
            ix += (lane >= d) ? u : 0;
        }
        wtot[t] = ix - x;   // exclusive wave base
    }
    __syncthreads();
    return inc - v + wtot[w];
}

// ---------------- binned CSR build ----------------
// Pass 1: per-chunk per-bin counts -> cnthist[bin][chunk] (stride NCH1)
__global__ __launch_bounds__(256) void k_hist(const int* __restrict__ ei,
                                              int* __restrict__ cnthist) {
    __shared__ int h[NB];
    int t = threadIdx.x;
    for (int i = t; i < NB; i += 256) h[i] = 0;
    __syncthreads();
    int b0 = blockIdx.x * CHUNK;
    int n = N_EDGES - b0; if (n > CHUNK) n = CHUNK;   // always multiple of 4
    for (int e = t * 4; e < n; e += 1024) {
        int4 d4 = *(const int4*)(ei + N_EDGES + b0 + e);
        atomicAdd(&h[d4.x >> BINSHIFT], 1);
        atomicAdd(&h[d4.y >> BINSHIFT], 1);
        atomicAdd(&h[d4.z >> BINSHIFT], 1);
        atomicAdd(&h[d4.w >> BINSHIFT], 1);
    }
    __syncthreads();
    for (int i = t; i < NB; i += 256)
        cnthist[i * NCH1 + blockIdx.x] = h[i];
}

// Pass 2: per-bin exclusive scan over chunks (in-place) + sentinel column;
// bin totals out.  binscatter later recovers counts as pre[blk+1]-pre[blk].
__global__ __launch_bounds__(256) void k_colscan(int* __restrict__ cnthist,
                                                 int* __restrict__ colsum) {
    __shared__ int wtot[4];
    int i = blockIdx.x;   // bin
    int t = threadIdx.x;
    int lane = t & 63;
    int v[4];
    int s4 = 0;
#pragma unroll
    for (int u = 0; u < 4; ++u) {
        int idx = t * 4 + u;
        v[u] = (idx < NCH) ? cnthist[i * NCH1 + idx] : 0;
        s4 += v[u];
    }
    int inc = wincl(s4);
    if (lane == 63) wtot[t >> 6] = inc;
    __syncthreads();
    if (t < 4) {
        int x = wtot[t], ix = x;
#pragma unroll
        for (int d = 1; d < 4; d <<= 1) {
            int u2 = __shfl_up(ix, d, 64);
            ix += (lane >= d) ? u2 : 0;
        }
        wtot[t] = ix - x;
    }
    __syncthreads();
    int base = inc - s4 + wtot[t >> 6];   // exclusive across 4-groups
#pragma unroll
    for (int u = 0; u < 4; ++u) {
        int idx = t * 4 + u;
        if (idx < NCH) cnthist[i * NCH1 + idx] = base;
        base += v[u];
    }
    if (t == 255) {                        // base here == bin total
        cnthist[i * NCH1 + NCH] = base;    // sentinel column
        colsum[i] = base;
    }
}

// Pass 3: scan of 391 bin totals -> binbase (single block)
__global__ __launch_bounds__(512) void k_scanbins(const int* __restrict__ colsum,
                                                  int* __restrict__ binbase) {
    __shared__ int wtot[8];
    int t = threadIdx.x;
    int v = (t < NB) ? colsum[t] : 0;
    int pre = blkexcl512(v, wtot);
    if (t < NB) binbase[t] = pre;
    if (t == 0) binbase[NB] = N_EDGES;   // sentinel
}

// Pass 4: scatter edges into bin buckets.  Per-chunk per-bin counts come from
// the scanned cnthist (pre[blk+1]-pre[blk]) -- NO edge-decode pre-pass.
// Single edge pass sorts into LDS, then linear dump (clustered writes).
__global__ __launch_bounds__(512) void k_binscatter(const int* __restrict__ ei,
                                                    const int* __restrict__ binbase,
                                                    const int* __restrict__ cnthist,
                                                    unsigned* __restrict__ binbuf) {
    __shared__ unsigned       srecS[CHUNK];  // records at sorted position (24KB)
    __shared__ unsigned short sbinS[CHUNK];  // bin at sorted position     (12KB)
    __shared__ int h[NB], rl[NB], gb[NB];
    __shared__ int wtot[8];
    int t = threadIdx.x;
    int b0 = blockIdx.x * CHUNK;
    int n = N_EDGES - b0; if (n > CHUNK) n = CHUNK;
    int pre_b = 0, c = 0;
    if (t < NB) {
        pre_b = cnthist[t * NCH1 + blockIdx.x];
        c = cnthist[t * NCH1 + blockIdx.x + 1] - pre_b;
    }
    int rlv = blkexcl512(c, wtot);   // chunk-local sorted base per bin
    if (t < NB) {
        rl[t] = rlv;
        gb[t] = binbase[t] + pre_b;  // global dump base
        h[t] = 0;                    // cursor
    }
    __syncthreads();
    for (int e = t; e < n; e += 512) {
        int d = ei[N_EDGES + b0 + e];
        int s = ei[b0 + e];
        int b = d >> BINSHIFT;
        int p = rl[b] + atomicAdd(&h[b], 1);
        srecS[p] = (unsigned)s | ((unsigned)(d & (BINSZ - 1)) << 17);  // s < 2^17
        sbinS[p] = (unsigned short)b;
    }
    __syncthreads();
    for (int p = t; p < n; p += 512) {
        int b = sbinS[p];
        binbuf[gb[b] + (p - rl[b])] = srecS[p];
    }
}

// Pass 5: within each bin, per-node counting sort -> csr_src, rowstart, dinv.
// Half-bin split (782 blocks); bin records STAGED IN LDS on the count pass,
// scatter pass reads LDS (halves global read traffic; kills 2nd-pass latency).
__global__ __launch_bounds__(512) void k_binfill(const unsigned* __restrict__ binbuf,
                                                 const int* __restrict__ binbase,
                                                 int* __restrict__ rowstart,
                                                 float* __restrict__ dinv,
                                                 int* __restrict__ csr_src) {
    int bb = blockIdx.x;
    int b = bb >> 1;        // bin
    int half = bb & 1;      // node range [half*128, half*128+128)
    int t = threadIdx.x;
    __shared__ unsigned srec[FCAP];   // 36KB staging
    __shared__ int cnt[BINSZ], rloc[BINSZ], cur[BINSZ], wtot[8];
    int ebeg = binbase[b], eend = binbase[b + 1];
    int m = eend - ebeg;
    if (t < BINSZ) cnt[t] = 0;
    __syncthreads();
    for (int e = t; e < m; e += 512) {
        unsigned v = binbuf[ebeg + e];
        if (e < FCAP) srec[e] = v;
        atomicAdd(&cnt[v >> 17], 1);
    }
    __syncthreads();
    int c = (t < BINSZ) ? cnt[t] : 0;
    int pre = blkexcl512(c, wtot);
    if (t < BINSZ) {
        rloc[t] = pre;
        cur[t] = 0;
        int node = b * BINSZ + t;
        if ((t >> 7) == half && node < N_NODES) {
            rowstart[node] = ebeg + pre;
            dinv[node] = rsqrtf((float)c + 1.0f);  // +1 self-loop
        }
    }
    if (bb == 0 && t == 0) rowstart[N_NODES] = N_EDGES;  // sentinel
    __syncthreads();
    for (int e = t; e < m; e += 512) {
        unsigned vv = (e < FCAP) ? srec[e] : binbuf[ebeg + e];
        int dl = vv >> 17;
        if ((dl >> 7) == half) {
            int p = ebeg + rloc[dl] + atomicAdd(&cur[dl], 1);
            csr_src[p] = (int)(vv & 0x1FFFFu);
        }
    }
}

// ---------------- dense transform 1 (write dinv-scaled fp16, interleaved [node*32+j]) -----
__global__ void k_xw1(const float* __restrict__ x, const float* __restrict__ W1,
                      const float* __restrict__ dinv, __half* __restrict__ xwh) {
    int t = blockIdx.x * blockDim.x + threadIdx.x;
    int node = t >> 5;
    int j = t & 31;
    __shared__ float sW[IN_DIM * HID];
    __shared__ float sx[8 * IN_DIM];
    for (int i = threadIdx.x; i < IN_DIM * HID; i += 256) sW[i] = W1[i];
    int base = blockIdx.x * 8;
    if (threadIdx.x < 8 * IN_DIM) sx[threadIdx.x] = x[base * IN_DIM + threadIdx.x];
    __syncthreads();
    int ln = node - base;
    float acc = 0.0f;
#pragma unroll
    for (int k = 0; k < IN_DIM; ++k)
        acc += sx[ln * IN_DIM + k] * sW[k * HID + j];
    xwh[t] = __float2half(dinv[node] * acc);
}

// ---------------- wide edge gather (octet decomposition, unchanged) ----------------
__device__ __forceinline__ void accum8(float* __restrict__ acc, const uint4 v) {
    float2 f0 = __half22float2(*(const __half2*)&v.x);
    float2 f1 = __half22float2(*(const __half2*)&v.y);
    float2 f2 = __half22float2(*(const __half2*)&v.z);
    float2 f3 = __half22float2(*(const __half2*)&v.w);
    acc[0] += f0.x; acc[1] += f0.y;
    acc[2] += f1.x; acc[3] += f1.y;
    acc[4] += f2.x; acc[5] += f2.y;
    acc[6] += f3.x; acc[7] += f3.y;
}

__device__ __forceinline__ void edge_accum8(int beg, int end, int q, int oj,
                                            const int* __restrict__ csr_src,
                                            const __half* __restrict__ xwh,
                                            float* __restrict__ acc) {
#pragma unroll
    for (int k = 0; k < 8; ++k) acc[k] = 0.0f;
    int e = beg;
    for (; e + 32 <= end; e += 32) {
        int s0 = csr_src[e + q];
        int s1 = csr_src[e + 8 + q];
        int s2 = csr_src[e + 16 + q];
        int s3 = csr_src[e + 24 + q];
        uint4 v0 = *(const uint4*)(xwh + ((s0 << 5) | oj));
        uint4 v1 = *(const uint4*)(xwh + ((s1 << 5) | oj));
        uint4 v2 = *(const uint4*)(xwh + ((s2 << 5) | oj));
        uint4 v3 = *(const uint4*)(xwh + ((s3 << 5) | oj));
        accum8(acc, v0); accum8(acc, v1); accum8(acc, v2); accum8(acc, v3);
    }
    if (e + 16 <= end) {
        int s0 = csr_src[e + q];
        int s1 = csr_src[e + 8 + q];
        uint4 v0 = *(const uint4*)(xwh + ((s0 << 5) | oj));
        uint4 v1 = *(const uint4*)(xwh + ((s1 << 5) | oj));
        accum8(acc, v0); accum8(acc, v1);
        e += 16;
    }
    if (e + 8 <= end) {
        int s0 = csr_src[e + q];
        uint4 v0 = *(const uint4*)(xwh + ((s0 << 5) | oj));
        accum8(acc, v0);
        e += 8;
    }
    if (e + q < end) {  // masked tail
        int s0 = csr_src[e + q];
        uint4 v0 = *(const uint4*)(xwh + ((s0 << 5) | oj));
        accum8(acc, v0);
    }
#pragma unroll
    for (int m = 4; m <= 16; m <<= 1) {
#pragma unroll
        for (int k = 0; k < 8; ++k) acc[k] += __shfl_xor(acc[k], m);
    }
}

// ---------------- layer-1 gather fused with bias1+relu and the W2 transform ---------------
__global__ __launch_bounds__(256) void k_gather_xw2(const int* __restrict__ rowstart,
                                                    const float* __restrict__ dinv,
                                                    const int* __restrict__ csr_src,
                                                    const __half* __restrict__ xwh1,
                                                    const float* __restrict__ b1,
                                                    const float* __restrict__ W2,
                                                    __half* __restrict__ xwh2) {
    __shared__ float sW2[HID * HID];
    __shared__ float sA[8][33];
    __shared__ float sH[8][33];
    for (int i = threadIdx.x; i < HID * HID; i += 256) sW2[i] = W2[i];

    int ln = threadIdx.x >> 5;
    int node = blockIdx.x * 8 + ln;
    int l = threadIdx.x & 31;
    int q = l >> 2;
    int oj = (l & 3) << 3;

    float acc[8];
    edge_accum8(rowstart[node], rowstart[node + 1], q, oj, csr_src, xwh1, acc);
    if (q == 0) {
#pragma unroll
        for (int k = 0; k < 8; ++k) sA[ln][oj + k] = acc[k];
    }
    __syncthreads();

    int j = l;
    float dd = dinv[node];
    float hv = dd * (sA[ln][j] + __half2float(xwh1[node * HID + j])) + b1[j];
    sH[ln][j] = hv > 0.0f ? hv : 0.0f;
    __syncthreads();

    float a2 = 0.0f;
#pragma unroll
    for (int k = 0; k < HID; ++k) a2 += sH[ln][k] * sW2[k * HID + j];
    xwh2[node * HID + j] = __float2half(dd * a2);
}

// ---------------- layer-2 gather fused with bias2+relu and the output MLP ----------------
__global__ __launch_bounds__(256) void k_gather_mlp(const int* __restrict__ rowstart,
                                                    const float* __restrict__ dinv,
                                                    const int* __restrict__ csr_src,
                                                    const __half* __restrict__ xwh,
                                                    const float* __restrict__ b2,
                                                    const float* __restrict__ Wo1,
                                                    const float* __restrict__ bo1,
                                                    const float* __restrict__ Wo2,
                                                    const float* __restrict__ bo2,
                                                    float* __restrict__ out) {
    __shared__ float sW1[HID * HID2];
    __shared__ float sb1[HID2];
    __shared__ float sW2v[HID2];
    __shared__ float sb2[HID];
    __shared__ float sA[8][33];
    __shared__ float sH[8][33];
    for (int i = threadIdx.x; i < HID * HID2; i += 256) sW1[i] = Wo1[i];
    if (threadIdx.x < HID2) {
        sb1[threadIdx.x] = bo1[threadIdx.x];
        sW2v[threadIdx.x] = Wo2[threadIdx.x];
    }
    if (threadIdx.x < HID) sb2[threadIdx.x] = b2[threadIdx.x];

    int ln = threadIdx.x >> 5;
    int node = blockIdx.x * 8 + ln;
    int l = threadIdx.x & 31;
    int q = l >> 2;
    int oj = (l & 3) << 3;

    float acc[8];
    edge_accum8(rowstart[node], rowstart[node + 1], q, oj, csr_src, xwh, acc);
    if (q == 0) {
#pragma unroll
        for (int k = 0; k < 8; ++k) sA[ln][oj + k] = acc[k];
    }
    __syncthreads();

    int j = l;
    float dd = dinv[node];
    float hv = dd * (sA[ln][j] + __half2float(xwh[node * HID + j])) + sb2[j];
    sH[ln][j] = hv > 0.0f ? hv : 0.0f;
    __syncthreads();

    float val = 0.0f;
    if (j < HID2) {
        float a = sb1[j];
#pragma unroll
        for (int k = 0; k < HID; ++k) a += sH[ln][k] * sW1[k * HID2 + j];
        a = a > 0.0f ? a : (expf(a) - 1.0f);  // elu alpha=1
        val = a * sW2v[j];
    }
#pragma unroll
    for (int d = 16; d >= 1; d >>= 1) val += __shfl_down(val, d, 32);
    if (j == 0) out[node] = val + bo2[0];
}

extern "C" void kernel_launch(void* const* d_in, const int* in_sizes, int n_in,
                              void* d_out, int out_size, void* d_ws, size_t ws_size,
                              hipStream_t stream) {
    const float* x   = (const float*)d_in[0];
    const int*   ei  = (const int*)d_in[1];
    const float* W1  = (const float*)d_in[3];
    const float* b1  = (const float*)d_in[4];
    const float* W2  = (const float*)d_in[5];
    const float* b2  = (const float*)d_in[6];
    const float* Wo1 = (const float*)d_in[7];
    const float* bo1 = (const float*)d_in[8];
    const float* Wo2 = (const float*)d_in[9];
    const float* bo2 = (const float*)d_in[10];
    float* out = (float*)d_out;

    // ws layout (4B units):
    // colsum[512] | binbase[512] | rowstart[SCHUNK] | dinv[SCHUNK]
    // | csr_src[E] (cnthist[NB*NCH1]=204102 ints aliases here; dead before binfill writes)
    // | binbuf[E] | XWH1[N*HID fp16] | XWH2[N*HID fp16]
    int*      colsum   = (int*)d_ws;
    int*      binbase  = colsum + 512;
    int*      rowstart = binbase + 512;
    float*    dinv     = (float*)(rowstart + SCHUNK);
    int*      csr_src  = (int*)(dinv + SCHUNK);
    unsigned* binbuf   = (unsigned*)(csr_src + N_EDGES);
    __half*   XWH1     = (__half*)(binbuf + N_EDGES);
    __half*   XWH2     = XWH1 + (size_t)N_NODES * HID;
    int*      cnthist  = csr_src;   // alias: NB*NCH1 = 204102 ints << N_EDGES

    const int BT = 256;
    int gNH  = (N_NODES * HID + BT - 1) / BT;       // 12500
    int gG   = N_NODES / 8;                         // 12500 (exact)

    // binned CSR build: hist -> colscan(+sentinel) -> binscan -> scatter -> fill
    k_hist      <<<NCH, BT, 0, stream>>>(ei, cnthist);
    k_colscan   <<<NB, BT, 0, stream>>>(cnthist, colsum);
    k_scanbins  <<<1, 512, 0, stream>>>(colsum, binbase);
    k_binscatter<<<NCH, 512, 0, stream>>>(ei, binbase, cnthist, binbuf);
    k_binfill   <<<2 * NB, 512, 0, stream>>>(binbuf, binbase, rowstart, dinv, csr_src);

    // layer 1 (+ fused W2): XWH1 = fp16(dinv.*(x@W1)); XWH2 = fp16(dinv.*(relu(gather+b1)@W2))
    k_xw1<<<gNH, BT, 0, stream>>>(x, W1, dinv, XWH1);
    k_gather_xw2<<<gG, BT, 0, stream>>>(rowstart, dinv, csr_src, XWH1, b1, W2, XWH2);

    // layer 2 + head: out = MLP(relu(dinv.*gather(XWH2) + b2))
    k_gather_mlp<<<gG, BT, 0, stream>>>(rowstart, dinv, csr_src, XWH2,
                                        b2, Wo1, bo1, Wo2, bo2, out);
}